// Round 8
// baseline (134.535 us; speedup 1.0000x reference)
//
#include <hip/hip_runtime.h>

#define KS     11
#define HWDIM  512
#define IMG    (HWDIM*HWDIM)
#define TH     16
#define STRIPS 32              // 512 / TH
#define PLANES 96              // 32 images * 3 channels
#define EG     4               // guard entries (even/odd arrays) each side
#define EOW    264             // EG + 256 + EG
#define NPARTIAL (PLANES*STRIPS)   // 3072

__device__ __forceinline__ float ssim_px(float mu_u, float mu_v, float Su, float Sv)
{
    const float C1v = 1e-4f, C2v = 9e-4f, EPSV = 1e-8f;
    const float uu = mu_u*mu_u, vv = mu_v*mu_v;
    const float mu2d = 0.5f*(uu - vv);   // 2 mux muy
    const float mu2s = 0.5f*(uu + vv);   // mux^2 + muy^2
    const float Sd   = 0.5f*(Su - Sv);   // 2 conv(p't')
    const float Ss   = 0.5f*(Su + Sv);   // conv(p'^2)+conv(t'^2)
    const float A  = mu2d + C1v;
    const float B  = Sd - mu2d + C2v;
    const float Cc = mu2s + C1v;
    const float D  = Ss - mu2s + C2v;
    // den > 1e-8 always; v_rcp_f32 rel err ~1e-7 << 1.7e-4 threshold
    return A * B * __builtin_amdgcn_rcpf(Cc*D + EPSV);
}

// load input row Y, cols c0,c0+1; map u=p'+t', v=p'-t' (zero outside image)
#define LOADUV(Y, UA, VA, UB, VB) do {                                        \
    if ((unsigned)(Y) < HWDIM) {                                              \
        const float2 p2 = *(const float2*)(pR + (size_t)(Y)*HWDIM);           \
        const float2 t2 = *(const float2*)(tR + (size_t)(Y)*HWDIM);           \
        UA = 0.5f*(p2.x + t2.x) + 1.0f; VA = 0.5f*(p2.x - t2.x);              \
        UB = 0.5f*(p2.y + t2.y) + 1.0f; VB = 0.5f*(p2.y - t2.y);              \
    } else { UA = 0.f; VA = 0.f; UB = 0.f; VB = 0.f; }                        \
} while(0)

// one vertical tap from ring slot S, both columns, mean + 2nd moment
#define VTAP(W, S) do {                                                       \
    float t_;                                                                 \
    t_ = (W)*uA##S; muA += t_; SuA = fmaf(t_, uA##S, SuA);                    \
    t_ = (W)*vA##S; mvA += t_; SvA = fmaf(t_, vA##S, SvA);                    \
    t_ = (W)*uB##S; muB += t_; SuB = fmaf(t_, uB##S, SuB);                    \
    t_ = (W)*vB##S; mvB += t_; SvB = fmaf(t_, vB##S, SvB);                    \
} while(0)

#define HF(ACC, W, T) do {                                                    \
    ACC.x = fmaf((W), (T).x, ACC.x); ACC.y = fmaf((W), (T).y, ACC.y);         \
    ACC.z = fmaf((W), (T).z, ACC.z); ACC.w = fmaf((W), (T).w, ACC.w);         \
} while(0)

__global__ __launch_bounds__(256) void ssim_stream_kernel(
    const float* __restrict__ pred,
    const float* __restrict__ target,
    const float* __restrict__ kern,
    float* __restrict__ partial)
{
    __shared__ float4 hbufE[2][EOW];   // even cols: c=2i -> [EG+i]
    __shared__ float4 hbufO[2][EOW];   // odd  cols: c=2i+1 -> [EG+i]
    __shared__ float red[4];

    const int tid   = threadIdx.x;     // 0..255; owns cols 2tid, 2tid+1
    const int strip = blockIdx.x;      // 0..31
    const int plane = blockIdx.y;      // 0..95
    const int y0    = strip * TH;

    // exact 1D factors: a_j = k2d[5][j] / sqrt(k2d[5][5])
    const float inv_a5 = 1.0f / sqrtf(kern[60]);
    const float w0  = kern[55]*inv_a5,  w1 = kern[56]*inv_a5;
    const float w2  = kern[57]*inv_a5,  w3 = kern[58]*inv_a5;
    const float w4  = kern[59]*inv_a5,  w5 = kern[60]*inv_a5;
    const float w6  = kern[61]*inv_a5,  w7 = kern[62]*inv_a5;
    const float w8  = kern[63]*inv_a5,  w9 = kern[64]*inv_a5;
    const float w10 = kern[65]*inv_a5;

    const float* pR = pred   + (size_t)plane * IMG + 2*tid;
    const float* tR = target + (size_t)plane * IMG + 2*tid;

    // zero guard entries (cols <0 and >=512), both parities, both arrays;
    // ordered before any h-pass read by the first in-loop barrier
    if (tid < EG) {
        const float4 z = make_float4(0,0,0,0);
        hbufE[0][tid] = z;                 hbufE[1][tid] = z;
        hbufO[0][tid] = z;                 hbufO[1][tid] = z;
        hbufE[0][EG+256+tid] = z;          hbufE[1][EG+256+tid] = z;
        hbufO[0][EG+256+tid] = z;          hbufO[1][EG+256+tid] = z;
    }

    // vertical shift-ring: 11 slots x {u,v} x {colA,colB} — named scalars only
    float uA0,uA1,uA2,uA3,uA4,uA5,uA6,uA7,uA8,uA9,uA10;
    float vA0,vA1,vA2,vA3,vA4,vA5,vA6,vA7,vA8,vA9,vA10;
    float uB0,uB1,uB2,uB3,uB4,uB5,uB6,uB7,uB8,uB9,uB10;
    float vB0,vB1,vB2,vB3,vB4,vB5,vB6,vB7,vB8,vB9,vB10;
    float nuA, nvA, nuB, nvB;

    // entering iteration r=0: slots 1..10 hold rows y0-5..y0+4, prefetch y0+5
    uA0=0.f; vA0=0.f; uB0=0.f; vB0=0.f;
    LOADUV(y0-5, uA1, vA1, uB1, vB1);
    LOADUV(y0-4, uA2, vA2, uB2, vB2);
    LOADUV(y0-3, uA3, vA3, uB3, vB3);
    LOADUV(y0-2, uA4, vA4, uB4, vB4);
    LOADUV(y0-1, uA5, vA5, uB5, vB5);
    LOADUV(y0+0, uA6, vA6, uB6, vB6);
    LOADUV(y0+1, uA7, vA7, uB7, vB7);
    LOADUV(y0+2, uA8, vA8, uB8, vB8);
    LOADUV(y0+3, uA9, vA9, uB9, vB9);
    LOADUV(y0+4, uA10, vA10, uB10, vB10);
    LOADUV(y0+5, nuA, nvA, nuB, nvB);

    float lsum = 0.f;
    #pragma unroll 4
    for (int r = 0; r < TH; ++r) {
        // shift ring down one row (unroll-4 + copy-prop removes most movs)
        uA0=uA1; vA0=vA1; uB0=uB1; vB0=vB1;
        uA1=uA2; vA1=vA2; uB1=uB2; vB1=vB2;
        uA2=uA3; vA2=vA3; uB2=uB3; vB2=vB3;
        uA3=uA4; vA3=vA4; uB3=uB4; vB3=vB4;
        uA4=uA5; vA4=vA5; uB4=uB5; vB4=vB5;
        uA5=uA6; vA5=vA6; uB5=uB6; vB5=vB6;
        uA6=uA7; vA6=vA7; uB6=uB7; vB6=vB7;
        uA7=uA8; vA7=vA8; uB7=uB8; vB7=vB8;
        uA8=uA9; vA8=vA9; uB8=uB9; vB8=vB9;
        uA9=uA10; vA9=vA10; uB9=uB10; vB9=vB10;
        uA10=nuA; vA10=nvA; uB10=nuB; vB10=nvB;
        // prefetch next input row (consumed next iteration)
        LOADUV(y0 + r + 6, nuA, nvA, nuB, nvB);

        // vertical 11-tap conv: mu=conv(u), Su=conv(u^2); same for v; both cols
        float muA=0.f,mvA=0.f,SuA=0.f,SvA=0.f;
        float muB=0.f,mvB=0.f,SuB=0.f,SvB=0.f;
        VTAP(w0,0);  VTAP(w1,1);  VTAP(w2,2);  VTAP(w3,3);  VTAP(w4,4);
        VTAP(w5,5);  VTAP(w6,6);  VTAP(w7,7);  VTAP(w8,8);  VTAP(w9,9);
        VTAP(w10,10);

        float4* bE = &hbufE[r & 1][0];
        float4* bO = &hbufO[r & 1][0];
        bE[EG + tid] = make_float4(muA, mvA, SuA, SvA);
        bO[EG + tid] = make_float4(muB, mvB, SuB, SvB);
        __syncthreads();

        // horizontal 11-tap conv, window shared across the column pair.
        float4 accA = make_float4(0,0,0,0), accB = make_float4(0,0,0,0);
        {
            float4 e, o;
            o = bO[EG + tid - 3]; HF(accA, w0,  o);
            e = bE[EG + tid - 2]; HF(accA, w1,  e); HF(accB, w0,  e);
            o = bO[EG + tid - 2]; HF(accA, w2,  o); HF(accB, w1,  o);
            e = bE[EG + tid - 1]; HF(accA, w3,  e); HF(accB, w2,  e);
            o = bO[EG + tid - 1]; HF(accA, w4,  o); HF(accB, w3,  o);
            e = bE[EG + tid    ]; HF(accA, w5,  e); HF(accB, w4,  e);
            o = bO[EG + tid    ]; HF(accA, w6,  o); HF(accB, w5,  o);
            e = bE[EG + tid + 1]; HF(accA, w7,  e); HF(accB, w6,  e);
            o = bO[EG + tid + 1]; HF(accA, w8,  o); HF(accB, w7,  o);
            e = bE[EG + tid + 2]; HF(accA, w9,  e); HF(accB, w8,  e);
            o = bO[EG + tid + 2]; HF(accA, w10, o); HF(accB, w9,  o);
            e = bE[EG + tid + 3];                   HF(accB, w10, e);
        }
        lsum += ssim_px(accA.x, accA.y, accA.z, accA.w);
        lsum += ssim_px(accB.x, accB.y, accB.z, accB.w);
        // no trailing barrier: parity reuse at r+2 is ordered by barrier r+1
    }

    // deterministic block reduction (4 waves)
    #pragma unroll
    for (int off = 32; off > 0; off >>= 1)
        lsum += __shfl_down(lsum, off, 64);
    if ((tid & 63) == 0) red[tid >> 6] = lsum;
    __syncthreads();
    if (tid == 0)
        partial[plane * STRIPS + strip] = red[0] + red[1] + red[2] + red[3];
}

__global__ __launch_bounds__(64) void ssim_reduce_kernel(
    const float* __restrict__ partial,
    float* __restrict__ out)
{
    const int b    = blockIdx.x;    // image 0..31
    const int lane = threadIdx.x;   // 0..63
    // image b owns partials [96b, 96b+96): planes 3b..3b+2, 32 strips each
    float s = partial[b * 96 + lane];
    if (lane < 32) s += partial[b * 96 + 64 + lane];
    #pragma unroll
    for (int off = 32; off > 0; off >>= 1)
        s += __shfl_down(s, off, 64);
    if (lane == 0) out[b] = s * (1.0f / (3.0f * 512.0f * 512.0f));
}

extern "C" void kernel_launch(void* const* d_in, const int* in_sizes, int n_in,
                              void* d_out, int out_size, void* d_ws, size_t ws_size,
                              hipStream_t stream) {
    (void)in_sizes; (void)n_in; (void)out_size; (void)ws_size;
    const float* pred   = (const float*)d_in[0];
    const float* target = (const float*)d_in[1];
    const float* kern   = (const float*)d_in[2];
    float* out     = (float*)d_out;
    float* partial = (float*)d_ws;   // NPARTIAL * 4 = 12288 bytes

    dim3 grid(STRIPS, PLANES);
    ssim_stream_kernel<<<grid, 256, 0, stream>>>(pred, target, kern, partial);
    ssim_reduce_kernel<<<32, 64, 0, stream>>>(partial, out);
}

// Round 9
// 98.774 us; speedup vs baseline: 1.3621x; 1.3621x over previous
//
#include <hip/hip_runtime.h>

typedef float v2f __attribute__((ext_vector_type(2)));
typedef float v4f __attribute__((ext_vector_type(4)));

#define KS     11
#define HWDIM  512
#define IMG    (HWDIM*HWDIM)
#define TH     32
#define STRIPS 16              // 512 / TH
#define PLANES 96              // 32 images * 3 channels
#define EG     4               // guard entries (even/odd arrays) each side
#define EOW    264             // EG + 256 + EG
#define NPARTIAL (PLANES*STRIPS)   // 1536

__device__ __forceinline__ float ssim_px(float mu_u, float mu_v, float Su, float Sv)
{
    const float C1v = 1e-4f, C2v = 9e-4f, EPSV = 1e-8f;
    const float uu = mu_u*mu_u, vv = mu_v*mu_v;
    const float mu2d = 0.5f*(uu - vv);   // 2 mux muy
    const float mu2s = 0.5f*(uu + vv);   // mux^2 + muy^2
    const float Sd   = 0.5f*(Su - Sv);   // 2 conv(p't')
    const float Ss   = 0.5f*(Su + Sv);   // conv(p'^2)+conv(t'^2)
    const float A  = mu2d + C1v;
    const float B  = Sd - mu2d + C2v;
    const float Cc = mu2s + C1v;
    const float D  = Ss - mu2s + C2v;
    // den > 1e-8 always; v_rcp_f32 rel err ~1e-7 << 1.7e-4 threshold
    return A * B * __builtin_amdgcn_rcpf(Cc*D + EPSV);
}

// load input row Y, cols 2t,2t+1; A/B = (u,v) per col, u=p'+t', v=p'-t'
#define LOADUV(Y, A, B) do {                                                  \
    if ((unsigned)(Y) < HWDIM) {                                              \
        const v2f p2 = *(const v2f*)(pR + (size_t)(Y)*HWDIM);                 \
        const v2f t2 = *(const v2f*)(tR + (size_t)(Y)*HWDIM);                 \
        A = (v2f){0.5f*(p2.x + t2.x) + 1.0f, 0.5f*(p2.x - t2.x)};             \
        B = (v2f){0.5f*(p2.y + t2.y) + 1.0f, 0.5f*(p2.y - t2.y)};             \
    } else { A = (v2f)(0.f); B = (v2f)(0.f); }                                \
} while(0)

// one vertical tap from ring slot S, both columns; packed (u,v) chains:
// mA=(mu,mv), SA=(Su,Sv) -> 6 v_pk ops per tap instead of 12 scalar
#define VTAP(W, S) do {                                                       \
    const v2f tA_ = (W) * A##S;                                               \
    mA += tA_;  SA = __builtin_elementwise_fma(tA_, A##S, SA);                \
    const v2f tB_ = (W) * B##S;                                               \
    mB += tB_;  SB = __builtin_elementwise_fma(tB_, B##S, SB);                \
} while(0)

// one horizontal tap: 4-field packed fma (2x v_pk_fma_f32)
#define HF(ACC, W, T)                                                         \
    ACC = __builtin_elementwise_fma((v4f){(W),(W),(W),(W)}, (T), ACC)

__global__ __launch_bounds__(256) void ssim_stream_kernel(
    const float* __restrict__ pred,
    const float* __restrict__ target,
    const float* __restrict__ kern,
    float* __restrict__ partial)
{
    __shared__ v4f hbufE[2][EOW];   // even cols: c=2i -> [EG+i], (mu,mv,Su,Sv)
    __shared__ v4f hbufO[2][EOW];   // odd  cols: c=2i+1 -> [EG+i]
    __shared__ float red[4];

    const int tid   = threadIdx.x;     // 0..255; owns cols 2tid, 2tid+1
    const int strip = blockIdx.x;      // 0..15
    const int plane = blockIdx.y;      // 0..95
    const int y0    = strip * TH;

    // exact 1D factors: a_j = k2d[5][j] / sqrt(k2d[5][5]); uniform -> SGPRs
    const float inv_a5 = 1.0f / sqrtf(kern[60]);
    const float w0  = kern[55]*inv_a5,  w1 = kern[56]*inv_a5;
    const float w2  = kern[57]*inv_a5,  w3 = kern[58]*inv_a5;
    const float w4  = kern[59]*inv_a5,  w5 = kern[60]*inv_a5;
    const float w6  = kern[61]*inv_a5,  w7 = kern[62]*inv_a5;
    const float w8  = kern[63]*inv_a5,  w9 = kern[64]*inv_a5;
    const float w10 = kern[65]*inv_a5;

    const float* pR = pred   + (size_t)plane * IMG + 2*tid;
    const float* tR = target + (size_t)plane * IMG + 2*tid;

    // zero guard entries (cols <0 and >=512), both parities, both arrays;
    // ordered before any h-pass read by the first in-loop barrier
    if (tid < EG) {
        const v4f z = (v4f)(0.f);
        hbufE[0][tid] = z;                 hbufE[1][tid] = z;
        hbufO[0][tid] = z;                 hbufO[1][tid] = z;
        hbufE[0][EG+256+tid] = z;          hbufE[1][EG+256+tid] = z;
        hbufO[0][EG+256+tid] = z;          hbufO[1][EG+256+tid] = z;
    }

    // vertical shift-ring: 11 slots x (u,v)-pair x {colA,colB} — named v2f only
    v2f A0,A1,A2,A3,A4,A5,A6,A7,A8,A9,A10;
    v2f B0,B1,B2,B3,B4,B5,B6,B7,B8,B9,B10;
    v2f nA, nB;

    // entering iteration r=0: slots 1..10 hold rows y0-5..y0+4, prefetch y0+5
    A0 = (v2f)(0.f); B0 = (v2f)(0.f);
    LOADUV(y0-5, A1, B1);
    LOADUV(y0-4, A2, B2);
    LOADUV(y0-3, A3, B3);
    LOADUV(y0-2, A4, B4);
    LOADUV(y0-1, A5, B5);
    LOADUV(y0+0, A6, B6);
    LOADUV(y0+1, A7, B7);
    LOADUV(y0+2, A8, B8);
    LOADUV(y0+3, A9, B9);
    LOADUV(y0+4, A10, B10);
    LOADUV(y0+5, nA, nB);

    float lsum = 0.f;
    for (int r = 0; r < TH; ++r) {
        // shift ring down one row
        A0=A1; B0=B1; A1=A2; B1=B2; A2=A3; B2=B3; A3=A4; B3=B4; A4=A5; B4=B5;
        A5=A6; B5=B6; A6=A7; B6=B7; A7=A8; B7=B8; A8=A9; B8=B9; A9=A10; B9=B10;
        A10=nA; B10=nB;
        // prefetch next input row (consumed next iteration)
        LOADUV(y0 + r + 6, nA, nB);

        // vertical 11-tap conv, packed: mA=(mu,mv), SA=(Su,Sv) per col
        v2f mA = (v2f)(0.f), SA = (v2f)(0.f);
        v2f mB = (v2f)(0.f), SB = (v2f)(0.f);
        VTAP(w0,0);  VTAP(w1,1);  VTAP(w2,2);  VTAP(w3,3);  VTAP(w4,4);
        VTAP(w5,5);  VTAP(w6,6);  VTAP(w7,7);  VTAP(w8,8);  VTAP(w9,9);
        VTAP(w10,10);

        v4f* bE = &hbufE[r & 1][0];
        v4f* bO = &hbufO[r & 1][0];
        bE[EG + tid] = (v4f){mA.x, mA.y, SA.x, SA.y};
        bO[EG + tid] = (v4f){mB.x, mB.y, SB.x, SB.y};
        __syncthreads();

        // horizontal 11-tap conv, window shared across the column pair.
        v4f accA = (v4f)(0.f), accB = (v4f)(0.f);
        {
            v4f e, o;
            o = bO[EG + tid - 3]; HF(accA, w0,  o);
            e = bE[EG + tid - 2]; HF(accA, w1,  e); HF(accB, w0,  e);
            o = bO[EG + tid - 2]; HF(accA, w2,  o); HF(accB, w1,  o);
            e = bE[EG + tid - 1]; HF(accA, w3,  e); HF(accB, w2,  e);
            o = bO[EG + tid - 1]; HF(accA, w4,  o); HF(accB, w3,  o);
            e = bE[EG + tid    ]; HF(accA, w5,  e); HF(accB, w4,  e);
            o = bO[EG + tid    ]; HF(accA, w6,  o); HF(accB, w5,  o);
            e = bE[EG + tid + 1]; HF(accA, w7,  e); HF(accB, w6,  e);
            o = bO[EG + tid + 1]; HF(accA, w8,  o); HF(accB, w7,  o);
            e = bE[EG + tid + 2]; HF(accA, w9,  e); HF(accB, w8,  e);
            o = bO[EG + tid + 2]; HF(accA, w10, o); HF(accB, w9,  o);
            e = bE[EG + tid + 3];                   HF(accB, w10, e);
        }
        lsum += ssim_px(accA.x, accA.y, accA.z, accA.w);
        lsum += ssim_px(accB.x, accB.y, accB.z, accB.w);
        // no trailing barrier: parity reuse at r+2 is ordered by barrier r+1
    }

    // deterministic block reduction (4 waves)
    #pragma unroll
    for (int off = 32; off > 0; off >>= 1)
        lsum += __shfl_down(lsum, off, 64);
    if ((tid & 63) == 0) red[tid >> 6] = lsum;
    __syncthreads();
    if (tid == 0)
        partial[plane * STRIPS + strip] = red[0] + red[1] + red[2] + red[3];
}

__global__ __launch_bounds__(64) void ssim_reduce_kernel(
    const float* __restrict__ partial,
    float* __restrict__ out)
{
    const int b    = blockIdx.x;    // image 0..31
    const int lane = threadIdx.x;   // 0..63
    // image b owns partials [48b, 48b+48): planes 3b..3b+2, 16 strips each
    float s = (lane < 48) ? partial[b * 48 + lane] : 0.f;
    #pragma unroll
    for (int off = 32; off > 0; off >>= 1)
        s += __shfl_down(s, off, 64);
    if (lane == 0) out[b] = s * (1.0f / (3.0f * 512.0f * 512.0f));
}

extern "C" void kernel_launch(void* const* d_in, const int* in_sizes, int n_in,
                              void* d_out, int out_size, void* d_ws, size_t ws_size,
                              hipStream_t stream) {
    (void)in_sizes; (void)n_in; (void)out_size; (void)ws_size;
    const float* pred   = (const float*)d_in[0];
    const float* target = (const float*)d_in[1];
    const float* kern   = (const float*)d_in[2];
    float* out     = (float*)d_out;
    float* partial = (float*)d_ws;   // NPARTIAL * 4 = 6144 bytes

    dim3 grid(STRIPS, PLANES);
    ssim_stream_kernel<<<grid, 256, 0, stream>>>(pred, target, kern, partial);
    ssim_reduce_kernel<<<32, 64, 0, stream>>>(partial, out);
}